// Round 1
// baseline (750.504 us; speedup 1.0000x reference)
//
#include <hip/hip_runtime.h>
#include <hip/hip_bf16.h>

constexpr int BB  = 16384;   // batch
constexpr int CH  = 16;      // children per node
constexpr int SZ  = 256;     // SIZE
constexpr int KK  = 512;     // GEMM K = 2*SIZE
constexpr int NN  = 768;     // GEMM N = 3*SIZE

typedef float  f32x4 __attribute__((ext_vector_type(4)));
typedef short  s16x8 __attribute__((ext_vector_type(8)));

__device__ __forceinline__ unsigned short f2bf(float x) {
    unsigned u = __builtin_bit_cast(unsigned, x);
    unsigned r = u + 0x7fffu + ((u >> 16) & 1u);   // RNE
    return (unsigned short)(r >> 16);
}
__device__ __forceinline__ float sigmoidf_(float x) {
    return 1.0f / (1.0f + __expf(-x));
}
__device__ __forceinline__ void gload_lds16(const unsigned short* g, unsigned short* l) {
    __builtin_amdgcn_global_load_lds(
        (const __attribute__((address_space(1))) unsigned int*)g,
        (__attribute__((address_space(3))) unsigned int*)l,
        16, 0, 0);
}

// ---------------------------------------------------------------------------
// Kernel 1: [W_iou ; W_iou_track] (512x768 fp32) -> bf16 MFMA B-fragment order
//   Wsw[((nt*16+ks)*64+lane)*8+j] = Wcat[k][n], n=nt*16+(lane&15),
//   k=ks*32+(lane>>4)*8+j.  Also zero fcb[256].
// ---------------------------------------------------------------------------
__global__ void wprep(const float* __restrict__ Wiou,
                      const float* __restrict__ Wtrk,
                      unsigned short* __restrict__ Wsw,
                      float* __restrict__ fcb) {
    int g = blockIdx.x * 256 + threadIdx.x;   // 0 .. 49151
    if (g < 256) fcb[g] = 0.0f;
    if (g >= 48 * 16 * 64) return;
    int lane = g & 63;
    int ksnt = g >> 6;
    int ks = ksnt & 15;
    int nt = ksnt >> 4;
    int n  = nt * 16 + (lane & 15);
    int k0 = ks * 32 + (lane >> 4) * 8;
    unsigned short o8[8];
#pragma unroll
    for (int j = 0; j < 8; ++j) {
        int k = k0 + j;
        float v = (k < SZ) ? Wiou[k * NN + n] : Wtrk[(k - SZ) * NN + n];
        o8[j] = f2bf(v);
    }
    *(s16x8*)(Wsw + (size_t)g * 8) = *(s16x8*)o8;
}

// ---------------------------------------------------------------------------
// Kernel 2: fc_b[j] = sum_t sigmoid(b_f[j] + trk0.Wft[:,j] + ch_h[t].Wf[:,j])
//                     * ch_c[t][j]   for t = 0..15 (only segment 0 survives)
// ---------------------------------------------------------------------------
__global__ void fc16(const float* __restrict__ children,
                     const float* __restrict__ tracking,
                     const float* __restrict__ Wf,
                     const float* __restrict__ bf,
                     const float* __restrict__ Wft,
                     float* __restrict__ fcb) {
    int t = blockIdx.x;       // 0..15
    int j = threadIdx.x;      // 0..255
    float base = bf[j];
    for (int k = 0; k < SZ; ++k) base += tracking[k] * Wft[k * SZ + j];
    const float* ch = children + (size_t)t * KK;
    float s = 0.0f;
    for (int k = 0; k < SZ; ++k) s += ch[k] * Wf[k * SZ + j];
    atomicAdd(&fcb[j], sigmoidf_(base + s) * ch[SZ + j]);
}

// ---------------------------------------------------------------------------
// Kernel 3: fused {segment-mean + bf16 A-pack} + GEMM + epilogue.
// 256 blocks x 256 thr; wave w owns 16 rows (g16 = blk*4+w).
// A-fragments built in registers directly from children/tracking (no Apack
// intermediate): lane l, kstep ks<8 holds mean_h[row=l&15][ks*32+(l>>4)*8+j];
// ks>=8 holds tracking_h[row][(ks-8)*32+(l>>4)*8+j].
// W tiles double-buffered through LDS via global_load_lds(16B).
// ---------------------------------------------------------------------------
__global__ __launch_bounds__(256, 1) void gemm2(
        const float* __restrict__ children,
        const float* __restrict__ tracking,
        const unsigned short* __restrict__ Wsw,
        const float* __restrict__ biou,
        const float* __restrict__ fcb,
        float* __restrict__ out) {
    __shared__ __attribute__((aligned(16))) unsigned short Bst[2][3][16 * 64 * 8]; // 96 KB

    const int tid  = threadIdx.x;
    const int lane = tid & 63;
    const int w    = tid >> 6;
    const int l15  = lane & 15;
    const int l4   = lane >> 4;
    const int g16  = blockIdx.x * 4 + w;

    // stage column-tile ct (3 p-tiles x 16KB) into buffer buf
    auto kick = [&](int ct, int buf) {
#pragma unroll
        for (int i = 0; i < 12; ++i) {
            int chunk = w * 12 + i;          // 0..47
            int p  = chunk >> 4;
            int ck = chunk & 15;
            const unsigned short* gsrc =
                Wsw + ((size_t)(p * 16 + ct) * 16 * 64) * 8 + ck * 512 + lane * 8;
            gload_lds16(gsrc, &Bst[buf][p][ck * 512]);
        }
    };

    kick(0, 0);   // tile 0 streams in while we build the A fragments

    // ---- fused segment-mean + bf16 A-fragment build (was meanpack) ----
    const int row = g16 * 16 + l15;               // node index m
    s16x8 a[16];
    {
        const float* chp = children + ((size_t)row * CH) * KK;
#pragma unroll 1
        for (int ks = 0; ks < 8; ++ks) {
            const float* p = chp + ks * 32 + l4 * 8;
            f32x4 s0 = {0.f, 0.f, 0.f, 0.f};
            f32x4 s1 = {0.f, 0.f, 0.f, 0.f};
#pragma unroll
            for (int jj = 0; jj < CH; ++jj) {
                const f32x4* q = (const f32x4*)(p + (size_t)jj * KK);
                s0 += q[0];
                s1 += q[1];
            }
            s0 *= 0.0625f;
            s1 *= 0.0625f;
            unsigned short o8[8];
            o8[0] = f2bf(s0[0]); o8[1] = f2bf(s0[1]);
            o8[2] = f2bf(s0[2]); o8[3] = f2bf(s0[3]);
            o8[4] = f2bf(s1[0]); o8[5] = f2bf(s1[1]);
            o8[6] = f2bf(s1[2]); o8[7] = f2bf(s1[3]);
            a[ks] = *(s16x8*)o8;
        }
        const float* trp = tracking + (size_t)row * KK;   // tracking_h = first 256 floats
#pragma unroll
        for (int ks = 8; ks < 16; ++ks) {
            const f32x4* q = (const f32x4*)(trp + (ks - 8) * 32 + l4 * 8);
            f32x4 t0 = q[0], t1 = q[1];
            unsigned short o8[8];
            o8[0] = f2bf(t0[0]); o8[1] = f2bf(t0[1]);
            o8[2] = f2bf(t0[2]); o8[3] = f2bf(t0[3]);
            o8[4] = f2bf(t1[0]); o8[5] = f2bf(t1[1]);
            o8[6] = f2bf(t1[2]); o8[7] = f2bf(t1[3]);
            a[ks] = *(s16x8*)o8;
        }
    }

    for (int ct = 0; ct < 16; ++ct) {
        __syncthreads();                       // drains vmcnt -> tile ct landed
        if (ct < 15) kick(ct + 1, (ct + 1) & 1);
        const int buf = ct & 1;
        f32x4 acc0 = {}, acc1 = {}, acc2 = {};
#pragma unroll
        for (int ks = 0; ks < 16; ++ks) {
            s16x8 b0 = *(const s16x8*)&Bst[buf][0][(ks * 64 + lane) * 8];
            s16x8 b1 = *(const s16x8*)&Bst[buf][1][(ks * 64 + lane) * 8];
            s16x8 b2 = *(const s16x8*)&Bst[buf][2][(ks * 64 + lane) * 8];
            acc0 = __builtin_amdgcn_mfma_f32_16x16x32_bf16(a[ks], b0, acc0, 0, 0, 0);
            acc1 = __builtin_amdgcn_mfma_f32_16x16x32_bf16(a[ks], b1, acc1, 0, 0, 0);
            acc2 = __builtin_amdgcn_mfma_f32_16x16x32_bf16(a[ks], b2, acc2, 0, 0, 0);
        }
        // epilogue for columns colj = ct*16 + l15
        int colj = ct * 16 + l15;
        float fb = fcb[colj];
        float bi = biou[colj];
        float bo = biou[SZ + colj];
        float bu = biou[2 * SZ + colj];
#pragma unroll
        for (int r = 0; r < 4; ++r) {
            int m = g16 * 16 + l4 * 4 + r;
            float vi = acc0[r] + bi;
            float vo = acc1[r] + bo;
            float vu = acc2[r] + bu;
            float i_ = sigmoidf_(vi);
            float o_ = sigmoidf_(vo);
            float u_ = 2.0f / (1.0f + __expf(-2.0f * vu)) - 1.0f;  // tanh
            float c_ = i_ * u_ + fb;
            float h_ = o_ * c_;
            size_t ob = (size_t)m * KK;
            out[ob + colj]      = h_;
            out[ob + SZ + colj] = c_;
        }
    }
}

// ---------------------------------------------------------------------------
extern "C" void kernel_launch(void* const* d_in, const int* in_sizes, int n_in,
                              void* d_out, int out_size, void* d_ws, size_t ws_size,
                              hipStream_t stream) {
    const float* children = (const float*)d_in[0];
    const float* tracking = (const float*)d_in[1];
    const float* Wiou     = (const float*)d_in[2];
    const float* biou     = (const float*)d_in[3];
    const float* Wf       = (const float*)d_in[4];
    const float* bf       = (const float*)d_in[5];
    const float* Wiout    = (const float*)d_in[6];
    const float* Wft      = (const float*)d_in[7];
    float* out = (float*)d_out;

    unsigned short* Wsw = (unsigned short*)d_ws;              // 768 KB
    float*          fcb = (float*)((char*)d_ws + (1 << 20));  // 1 KB @ 1MB

    hipLaunchKernelGGL(wprep, dim3(192), dim3(256), 0, stream, Wiou, Wiout, Wsw, fcb);
    hipLaunchKernelGGL(fc16, dim3(16), dim3(256), 0, stream,
                       children, tracking, Wf, bf, Wft, fcb);
    hipLaunchKernelGGL(gemm2, dim3(BB / 64), dim3(256), 0, stream,
                       children, tracking, Wsw, biou, fcb, out);
}